// Round 1
// 274.593 us; speedup vs baseline: 1.0024x; 1.0024x over previous
//
#include <hip/hip_runtime.h>
#include <stdint.h>

#define B_ROWS 8192
#define I_DIM  1024
#define N_DIM  1024
#define NDEG   9                  // D+1 (d = 0..8)
#define K_DIM  (I_DIM * (NDEG-1)) // 8192; k = (d-1)*1024 + i, d = 1..8 (d=0 folded into bias)

#define BM 256
#define BN 128
#define BK 64
#define NT (K_DIM / BK)           // 128 K-tiles

typedef __attribute__((ext_vector_type(8)))  short short8;
typedef __attribute__((ext_vector_type(16))) float f32x16;

__device__ __forceinline__ unsigned short f2bf(float f) {
  union { float f; uint32_t u; } v; v.f = f;
  uint32_t u = v.u;
  u += 0x7FFFu + ((u >> 16) & 1u);   // round-to-nearest-even
  return (unsigned short)(u >> 16);
}

__device__ __forceinline__ float bf2f(unsigned short h) {
  union { uint32_t u; float f; } v; v.u = ((uint32_t)h) << 16;
  return v.f;
}

// LDS chunk swizzle hash. For a 32-row fragment read (rows r0..r0+31, each lane
// one 16B chunk), conflict-freedom needs: within each {row mod 4} class of 8 rows,
// h(r)>>1 covers all 4 values twice (spreads the 32B bank-units). h(r)=(r>>2)&7
// satisfies this exactly; old (r&7)^((r>>2)&4) collapsed to 2 units -> 4-way.
__device__ __forceinline__ int h2(int r) { return (r >> 2) & 7; }

// ---------------- fused prep: repack (blocks < repack_blocks) + basis (rest) ----------
// repack: C[i,o,d] fp32 -> Bt[o,(d-1)*1024+i] bf16 (d>=1), bias[o] += sum_i C[i,o,0]
// basis : x[b,i] -> A[b,(d-1)*1024+i] = T_d(clip(tanh(x))), d=1..8
__global__ __launch_bounds__(256) void prep_kernel(const float* __restrict__ x,
                                                   const float* __restrict__ cf,
                                                   unsigned short* __restrict__ A,
                                                   unsigned short* __restrict__ Bt,
                                                   float* __restrict__ bias,
                                                   int repack_blocks) {
  __shared__ unsigned short L[32][584];   // [i_local][o_local*9+d], padded
  const int tid = threadIdx.x;

  if ((int)blockIdx.x < repack_blocks) {
    const int bx = blockIdx.x;
    const int i0 = (bx & 31) * 32;
    const int o0 = (bx >> 5) * 64;

    #pragma unroll
    for (int j = 0; j < 18; ++j) {               // 18*256 = 4608 float4 = 32*576 floats
      const int f4  = j * 256 + tid;
      const int il  = f4 / 144;
      const int odq = f4 % 144;
      const float4 v = *reinterpret_cast<const float4*>(
          cf + ((size_t)(i0 + il) * N_DIM + o0) * NDEG + (size_t)odq * 4);
      ushort4 w;
      w.x = f2bf(v.x); w.y = f2bf(v.y); w.z = f2bf(v.z); w.w = f2bf(v.w);
      *reinterpret_cast<ushort4*>(&L[il][odq * 4]) = w;
    }
    __syncthreads();

    for (int od = tid; od < 576; od += 256) {    // od = o_local*9 + d
      const int o = od / 9, d = od % 9;
      if (d == 0) {
        float s = 0.f;
        #pragma unroll
        for (int il = 0; il < 32; ++il) s += bf2f(L[il][od]);
        atomicAdd(&bias[o0 + o], s);
      } else {
        const size_t base = (size_t)(o0 + o) * K_DIM + (size_t)(d - 1) * I_DIM + i0;
        #pragma unroll
        for (int ci = 0; ci < 4; ++ci) {         // 4 x 8 consecutive i = 64B line
          uint32_t uu[4];
          #pragma unroll
          for (int p = 0; p < 4; ++p) {
            unsigned short lo = L[ci * 8 + p * 2 + 0][od];
            unsigned short hi = L[ci * 8 + p * 2 + 1][od];
            uu[p] = (uint32_t)lo | ((uint32_t)hi << 16);
          }
          uint4 u; u.x = uu[0]; u.y = uu[1]; u.z = uu[2]; u.w = uu[3];
          *reinterpret_cast<uint4*>(Bt + base + ci * 8) = u;
        }
      }
    }
  } else {
    const int b  = blockIdx.x - repack_blocks;
    const int i0 = tid * 4;
    const float4 xv = *reinterpret_cast<const float4*>(x + (size_t)b * I_DIM + i0);
    float t[4];
    t[0] = fminf(fmaxf(tanhf(xv.x), -0.999f), 0.999f);
    t[1] = fminf(fmaxf(tanhf(xv.y), -0.999f), 0.999f);
    t[2] = fminf(fmaxf(tanhf(xv.z), -0.999f), 0.999f);
    t[3] = fminf(fmaxf(tanhf(xv.w), -0.999f), 0.999f);

    unsigned short* outb = A + (size_t)b * K_DIM + i0;
    float Tp[4] = {1.f, 1.f, 1.f, 1.f};
    float Tc[4] = {t[0], t[1], t[2], t[3]};
    #pragma unroll
    for (int d = 1; d < NDEG; ++d) {
      ushort4 o4;
      o4.x = f2bf(Tc[0]); o4.y = f2bf(Tc[1]); o4.z = f2bf(Tc[2]); o4.w = f2bf(Tc[3]);
      *reinterpret_cast<ushort4*>(outb + (size_t)(d - 1) * I_DIM) = o4;
      if (d < NDEG - 1) {
        #pragma unroll
        for (int j = 0; j < 4; ++j) {
          float Tn = 2.0f * t[j] * Tc[j] - Tp[j];
          Tp[j] = Tc[j]; Tc[j] = Tn;
        }
      }
    }
  }
}

// ---------------- GEMM: C[m,n] = bias[n] + sum_k A[m,k]*Bt[n,k] -------------------------
// 256x128 tile, BK=64, 512 threads = 8 waves (4M x 2N, 64x64 per wave), double-buffered
// LDS (96 KB dynamic), counted-vmcnt pipeline (never drains to 0 in main loop), raw
// s_barrier, setprio around MFMA clusters, h2 chunk swizzle on stage-source + ds_read.
__global__ __launch_bounds__(512, 2) void gemm_kernel(const unsigned short* __restrict__ A,
                                                      const unsigned short* __restrict__ Bt,
                                                      const float* __restrict__ bias,
                                                      float* __restrict__ C) {
  extern __shared__ unsigned short sm[];   // As: [2][256*64] @0 ; Bs: [2][128*64] @32768
  const int tid  = threadIdx.x;
  const int lane = tid & 63;
  const int wave = tid >> 6;        // 0..7
  const int l31  = lane & 31;
  const int half = lane >> 5;       // 0..1 -> k-offset 8*half
  const int wm   = wave >> 1;       // 0..3
  const int wn   = wave & 1;        // 0..1
  const int m0   = blockIdx.x * BM;
  const int n0   = blockIdx.y * BN;

  const int sr   = tid >> 3;        // 0..63 (staging row within issue group)
  const int slot = tid & 7;         // 16B chunk slot within 128B row

  const unsigned short* Abase = A  + (size_t)m0 * K_DIM;
  const unsigned short* Bbase = Bt + (size_t)n0 * K_DIM;

  f32x16 acc[2][2];
  #pragma unroll
  for (int a = 0; a < 2; ++a)
    #pragma unroll
    for (int b = 0; b < 2; ++b)
      #pragma unroll
      for (int r = 0; r < 16; ++r)
        acc[a][b][r] = 0.f;

#define STAGE_A(s, bf, kk) { const int r_ = (s)*64 + sr; const int gc_ = slot ^ h2(r_);     \
    __builtin_amdgcn_global_load_lds(                                                       \
        (const __attribute__((address_space(1))) void*)(Abase + (size_t)r_*K_DIM + (kk) + gc_*8), \
        (__attribute__((address_space(3))) void*)&sm[(bf)*16384 + r_*64 + slot*8], 16, 0, 0); }
#define STAGE_B(s, bf, kk) { const int r_ = (s)*64 + sr; const int gc_ = slot ^ h2(r_);     \
    __builtin_amdgcn_global_load_lds(                                                       \
        (const __attribute__((address_space(1))) void*)(Bbase + (size_t)r_*K_DIM + (kk) + gc_*8), \
        (__attribute__((address_space(3))) void*)&sm[32768 + (bf)*8192 + r_*64 + slot*8], 16, 0, 0); }

  // prologue: stage tile 0 into buf 0 (6 loads/thread)
  STAGE_A(0, 0, 0) STAGE_A(1, 0, 0) STAGE_A(2, 0, 0) STAGE_A(3, 0, 0)
  STAGE_B(0, 0, 0) STAGE_B(1, 0, 0)

  const int rowA0 = wm * 64 + l31;
  const int rowA1 = wm * 64 + 32 + l31;
  const int rowB0 = wn * 64 + l31;
  const int rowB1 = wn * 64 + 32 + l31;

  for (int kt = 0; kt < NT; ++kt) {
    const int  cur  = kt & 1;
    const int  nxt  = cur ^ 1;
    const int  k1   = (kt + 1) * BK;
    const bool more = (kt + 1 < NT);
    const unsigned short* Asc = &sm[cur * 16384];
    const unsigned short* Bsc = &sm[32768 + cur * 8192];

    // ---- phase 0: validate tile kt; compute quadrant (0,0)
    if (more) { STAGE_A(0, nxt, k1) STAGE_A(1, nxt, k1) }
    if (more) asm volatile("s_waitcnt vmcnt(2)" ::: "memory");  // tile kt's 6 done; 2 in flight
    else      asm volatile("s_waitcnt vmcnt(0)" ::: "memory");
    __builtin_amdgcn_s_barrier();
    __builtin_amdgcn_sched_barrier(0);      // no ds_read may hoist above tile validation

    short8 av0[4], av1[4], bv0[4], bv1[4];
    #pragma unroll
    for (int ks = 0; ks < 4; ++ks) {
      const int c = ks * 2 + half;
      av0[ks] = *reinterpret_cast<const short8*>(&Asc[rowA0 * 64 + (c ^ h2(rowA0)) * 8]);
      bv0[ks] = *reinterpret_cast<const short8*>(&Bsc[rowB0 * 64 + (c ^ h2(rowB0)) * 8]);
    }
    __builtin_amdgcn_s_setprio(1);
    #pragma unroll
    for (int ks = 0; ks < 4; ++ks)
      acc[0][0] = __builtin_amdgcn_mfma_f32_32x32x16_bf16(av0[ks], bv0[ks], acc[0][0], 0, 0, 0);
    __builtin_amdgcn_s_setprio(0);
    __builtin_amdgcn_s_barrier();

    // ---- phase 1: read bv1, stage 2, compute quadrant (0,1)
    #pragma unroll
    for (int ks = 0; ks < 4; ++ks) {
      const int c = ks * 2 + half;
      bv1[ks] = *reinterpret_cast<const short8*>(&Bsc[rowB1 * 64 + (c ^ h2(rowB1)) * 8]);
    }
    if (more) { STAGE_A(2, nxt, k1) STAGE_A(3, nxt, k1) }
    __builtin_amdgcn_s_barrier();
    __builtin_amdgcn_s_setprio(1);
    #pragma unroll
    for (int ks = 0; ks < 4; ++ks)
      acc[0][1] = __builtin_amdgcn_mfma_f32_32x32x16_bf16(av0[ks], bv1[ks], acc[0][1], 0, 0, 0);
    __builtin_amdgcn_s_setprio(0);
    __builtin_amdgcn_s_barrier();

    // ---- phase 2: read av1, stage 2, compute quadrants (1,0) + (1,1)
    #pragma unroll
    for (int ks = 0; ks < 4; ++ks) {
      const int c = ks * 2 + half;
      av1[ks] = *reinterpret_cast<const short8*>(&Asc[rowA1 * 64 + (c ^ h2(rowA1)) * 8]);
    }
    if (more) { STAGE_B(0, nxt, k1) STAGE_B(1, nxt, k1) }
    __builtin_amdgcn_s_barrier();
    __builtin_amdgcn_s_setprio(1);
    #pragma unroll
    for (int ks = 0; ks < 4; ++ks) {
      acc[1][0] = __builtin_amdgcn_mfma_f32_32x32x16_bf16(av1[ks], bv0[ks], acc[1][0], 0, 0, 0);
      acc[1][1] = __builtin_amdgcn_mfma_f32_32x32x16_bf16(av1[ks], bv1[ks], acc[1][1], 0, 0, 0);
    }
    __builtin_amdgcn_s_setprio(0);
    __builtin_amdgcn_s_barrier();
    __builtin_amdgcn_sched_barrier(0);      // next-iter stages may not hoist above this barrier
  }
#undef STAGE_A
#undef STAGE_B

  // epilogue: 32x32 C/D layout col = lane&31, row = (reg&3) + 8*(reg>>2) + 4*(lane>>5)
  #pragma unroll
  for (int ni = 0; ni < 2; ++ni) {
    const int col  = n0 + wn * 64 + ni * 32 + l31;
    const float bc = bias[col];
    #pragma unroll
    for (int mi = 0; mi < 2; ++mi) {
      const int rbase = m0 + wm * 64 + mi * 32 + 4 * half;
      #pragma unroll
      for (int r = 0; r < 16; ++r) {
        const int row = rbase + (r & 3) + 8 * (r >> 2);
        C[(size_t)row * N_DIM + col] = acc[mi][ni][r] + bc;
      }
    }
  }
}

extern "C" void kernel_launch(void* const* d_in, const int* in_sizes, int n_in,
                              void* d_out, int out_size, void* d_ws, size_t ws_size,
                              hipStream_t stream) {
  const float* x      = (const float*)d_in[0];
  const float* coeffs = (const float*)d_in[1];
  float* y            = (float*)d_out;

  const size_t bt_bytes = (size_t)N_DIM * K_DIM * sizeof(unsigned short); // 16.78 MB
  unsigned short* Bt = (unsigned short*)d_ws;
  float* bias        = (float*)((char*)d_ws + bt_bytes);
  unsigned short* A  = (unsigned short*)((char*)d_ws + bt_bytes + 4096);

  // bias accumulator must start at zero (ws is poisoned 0xAA each call)
  hipMemsetAsync(bias, 0, N_DIM * sizeof(float), stream);

  // 96 KB dynamic LDS for the gemm (above the 64 KB default cap)
  hipFuncSetAttribute((const void*)gemm_kernel,
                      hipFuncAttributeMaxDynamicSharedMemorySize, 98304);

  // chunk M so (Bt + bias + A-chunk) fits in workspace; full A is ~134 MB
  size_t avail    = (ws_size > bt_bytes + 4096) ? (ws_size - bt_bytes - 4096) : 0;
  size_t rows_fit = avail / ((size_t)K_DIM * sizeof(unsigned short));
  int m_chunk = (int)((rows_fit / BM) * BM);
  if (m_chunk > B_ROWS) m_chunk = B_ROWS;
  if (m_chunk < BM)     m_chunk = BM;

  for (int m0 = 0; m0 < B_ROWS; m0 += m_chunk) {
    int mc = B_ROWS - m0; if (mc > m_chunk) mc = m_chunk;
    const int rb = (m0 == 0) ? 512 : 0;   // repack blocks only in the first chunk
    prep_kernel<<<rb + mc, 256, 0, stream>>>(x + (size_t)m0 * I_DIM, coeffs, A, Bt, bias, rb);
    gemm_kernel<<<dim3(mc / BM, N_DIM / BN), 512, 98304, stream>>>(
        A, Bt, bias, y + (size_t)m0 * N_DIM);
  }
}